// Round 19
// baseline (34.149 us; speedup 1.0000x reference)
//
#include <hip/hip_runtime.h>

// B=64, H=W=512, K=7, VALID conv -> 506x506.
// v18 = v17's asm-pinned counted-vmcnt pipeline with an ADDRESS DIET:
//  - saddr loads (v_off 32b + SGPR base): 7 VGPR addr pairs -> 4 voffsets.
//  - rotating buffer 4 -> 3 rows (vmcnt(6), 2-row lead still >> miss lat).
//  - target ~85 VGPR -> 5-6 waves/SIMD (v17: ~4), keeping MLP=9/wave.
// v17 post-mortem: ILP gain eaten by TLP loss; duty ~35%. This round buys
// waves without giving back in-flight loads.
#define HW 512
#define OW 506

typedef float vf4 __attribute__((ext_vector_type(4)));

// 3 x global_load_dwordx4, saddr form: 32-bit per-lane voffset + uniform
// SGPR base; rows reached via signed 13-bit immediates. "=&v" early-clobber
// (v15 fault fix).
#define LOAD_ROW(d0, d1, d2, voff, sbase, O0, O1, O2)                  \
    asm volatile("global_load_dwordx4 %0, %3, %4 offset:" #O0 "\n\t"   \
                 "global_load_dwordx4 %1, %3, %4 offset:" #O1 "\n\t"   \
                 "global_load_dwordx4 %2, %3, %4 offset:" #O2          \
                 : "=&v"(d0), "=&v"(d1), "=&v"(d2)                     \
                 : "v"(voff), "s"(sbase) : "memory")

// Counted wait; tied "+v" operands pin consumer FMAs after the waitcnt.
#define WAIT_ROW(d0, d1, d2, N)                                        \
    asm volatile("s_waitcnt vmcnt(" #N ")"                             \
                 : "+v"(d0), "+v"(d1), "+v"(d2))

template<int SH>
__device__ __forceinline__ void row_fma(int ir, const vf4 (&b)[3],
                                        const float (&wv)[49],
                                        float (&acc)[32]) {
#pragma unroll
    for (int kr = 0; kr < 7; ++kr) {
        const int s = ir - kr;               // constant after caller unroll
        if (s >= 0 && s < 8) {
#pragma unroll
            for (int kc = 0; kc < 7; ++kc) {
                const float wk = wv[kr * 7 + kc];
#pragma unroll
                for (int j = 0; j < 4; ++j) {
                    const int e = SH + kc + j;          // 0..11, constant
                    acc[s * 4 + j] = fmaf(wk, b[e >> 2][e & 3], acc[s * 4 + j]);
                }
            }
        }
    }
}

// Row r (0..13): voffset group g=r>>2 centered at row 4g+2; local = r&3
// -> immediate (local-2)*2048 + {0,16,32}, all within signed 13-bit.
template<int SH>
__device__ __forceinline__ void conv_pipe(int vg0, int vg1, int vg2, int vg3,
                                          unsigned long long sb,
                                          const float (&wv)[49],
                                          float (&acc)[32]) {
    vf4 b0[3], b1[3], b2[3];                 // 3-row rotating buffer (36 VGPR)

    // prologue: rows 0..2 -> 9 loads in flight
    LOAD_ROW(b0[0], b0[1], b0[2], vg0, sb, -4096, -4080, -4064);  // row 0
    LOAD_ROW(b1[0], b1[1], b1[2], vg0, sb, -2048, -2032, -2016);  // row 1
    LOAD_ROW(b2[0], b2[1], b2[2], vg0, sb,     0,    16,    32);  // row 2

    // steady: wait row ir (vmcnt(6) keeps 2 rows in flight), FMA, refill.
    WAIT_ROW(b0[0], b0[1], b0[2], 6);
    row_fma<SH>(0, b0, wv, acc);
    LOAD_ROW(b0[0], b0[1], b0[2], vg0, sb,  2048,  2064,  2080);  // row 3

    WAIT_ROW(b1[0], b1[1], b1[2], 6);
    row_fma<SH>(1, b1, wv, acc);
    LOAD_ROW(b1[0], b1[1], b1[2], vg1, sb, -4096, -4080, -4064);  // row 4

    WAIT_ROW(b2[0], b2[1], b2[2], 6);
    row_fma<SH>(2, b2, wv, acc);
    LOAD_ROW(b2[0], b2[1], b2[2], vg1, sb, -2048, -2032, -2016);  // row 5

    WAIT_ROW(b0[0], b0[1], b0[2], 6);
    row_fma<SH>(3, b0, wv, acc);
    LOAD_ROW(b0[0], b0[1], b0[2], vg1, sb,     0,    16,    32);  // row 6

    WAIT_ROW(b1[0], b1[1], b1[2], 6);
    row_fma<SH>(4, b1, wv, acc);
    LOAD_ROW(b1[0], b1[1], b1[2], vg1, sb,  2048,  2064,  2080);  // row 7

    WAIT_ROW(b2[0], b2[1], b2[2], 6);
    row_fma<SH>(5, b2, wv, acc);
    LOAD_ROW(b2[0], b2[1], b2[2], vg2, sb, -4096, -4080, -4064);  // row 8

    WAIT_ROW(b0[0], b0[1], b0[2], 6);
    row_fma<SH>(6, b0, wv, acc);
    LOAD_ROW(b0[0], b0[1], b0[2], vg2, sb, -2048, -2032, -2016);  // row 9

    WAIT_ROW(b1[0], b1[1], b1[2], 6);
    row_fma<SH>(7, b1, wv, acc);
    LOAD_ROW(b1[0], b1[1], b1[2], vg2, sb,     0,    16,    32);  // row 10

    WAIT_ROW(b2[0], b2[1], b2[2], 6);
    row_fma<SH>(8, b2, wv, acc);
    LOAD_ROW(b2[0], b2[1], b2[2], vg2, sb,  2048,  2064,  2080);  // row 11

    WAIT_ROW(b0[0], b0[1], b0[2], 6);
    row_fma<SH>(9, b0, wv, acc);
    LOAD_ROW(b0[0], b0[1], b0[2], vg3, sb, -4096, -4080, -4064);  // row 12

    WAIT_ROW(b1[0], b1[1], b1[2], 6);
    row_fma<SH>(10, b1, wv, acc);
    LOAD_ROW(b1[0], b1[1], b1[2], vg3, sb, -2048, -2032, -2016);  // row 13

    // epilogue: drain 6 -> 3 -> 0
    WAIT_ROW(b2[0], b2[1], b2[2], 6);
    row_fma<SH>(11, b2, wv, acc);
    WAIT_ROW(b0[0], b0[1], b0[2], 3);
    row_fma<SH>(12, b0, wv, acc);
    WAIT_ROW(b1[0], b1[1], b1[2], 0);
    row_fma<SH>(13, b1, wv, acc);
}

__global__ __launch_bounds__(256) void conv7x7_v18(
    const float* __restrict__ in,      // [64][512][512]
    const float* __restrict__ weight,  // [7][7]
    const float* __restrict__ bias,    // [1]
    float* __restrict__ out)           // [64][506][506]
{
    const int tid  = threadIdx.x;
    const int lane = tid & 63;
    const int w    = tid >> 6;
    const int bx   = blockIdx.x;                // 0 or 1
    const int x0   = bx ? 250 : 0;              // tiles cover 0..255, 250..505
    const int y0   = min((int)blockIdx.y * 32, OW - 32);  // shifted last tile
    const int yb   = y0 + w * 8;                // wave's first output row (<=498)
    const int b    = blockIdx.z;

    // ---- weights + bias -> SGPRs (uniform, statically indexed) ----
    float wv[49];
#pragma unroll
    for (int i = 0; i < 49; ++i)
        wv[i] = __uint_as_float(__builtin_amdgcn_readfirstlane(__float_as_uint(weight[i])));
    const float bv = __uint_as_float(__builtin_amdgcn_readfirstlane(__float_as_uint(bias[0])));

    const float* __restrict__ ib = in + (size_t)b * (HW * HW);
    const unsigned long long sb = (unsigned long long)ib;   // uniform SGPR base

    const int cb  = x0 + 4 * lane;              // first output col (<=502)
    const int cbl = cb - (bx ? 2 : 0);          // 16B-aligned window base
    // byte voffsets, one per 4-row group, centered at row 4g+2 (so all
    // row immediates are within the signed 13-bit range and voff >= 4096).
    const int base = (yb * HW + cbl) * 4;
    const int vg0  = base + 2  * 2048;
    const int vg1  = base + 6  * 2048;
    const int vg2  = base + 10 * 2048;
    const int vg3  = base + 14 * 2048;

    float acc[32];
#pragma unroll
    for (int i = 0; i < 32; ++i) acc[i] = 0.f;

    if (bx == 0) conv_pipe<0>(vg0, vg1, vg2, vg3, sb, wv, acc);
    else         conv_pipe<2>(vg0, vg1, vg2, vg3, sb, wv, acc);

    // ---- store: 8 rows x 4 cols, two float2 per row, unguarded ----
    float* __restrict__ outb = out + (size_t)b * (OW * OW);
#pragma unroll
    for (int s = 0; s < 8; ++s) {
        float* orow = outb + (size_t)(yb + s) * OW + cb;   // cb even -> 8B aligned
        *reinterpret_cast<float2*>(orow) =
            make_float2(acc[s * 4 + 0] + bv, acc[s * 4 + 1] + bv);
        *reinterpret_cast<float2*>(orow + 2) =
            make_float2(acc[s * 4 + 2] + bv, acc[s * 4 + 3] + bv);
    }
}

extern "C" void kernel_launch(void* const* d_in, const int* in_sizes, int n_in,
                              void* d_out, int out_size, void* d_ws, size_t ws_size,
                              hipStream_t stream) {
    const float* enc_x  = (const float*)d_in[0];
    const float* weight = (const float*)d_in[1];
    const float* bias   = (const float*)d_in[2];
    float* outp         = (float*)d_out;

    // x: 2 overlapping 256-col tiles; y: 16 tiles of 32 rows (last shifted);
    // z: 64 images. 2048 blocks = 8/CU.
    dim3 grid(2, 16, 64);
    dim3 block(256);
    hipLaunchKernelGGL(conv7x7_v18, grid, block, 0, stream,
                       enc_x, weight, bias, outp);
}

// Round 22
// 33.167 us; speedup vs baseline: 1.0296x; 1.0296x over previous
//
#include <hip/hip_runtime.h>

// B=64, H=W=512, K=7, VALID conv -> 506x506.
// v21 = v17 engine (asm-pinned 4-row counted-vmcnt pipeline, 4x8 micro-tile,
// guard-free shifted tiling -- 33.2us, stable) + XCD-AWARE BLOCK SWIZZLE.
// v19/v20 (cross-image prefetch) crashed twice -> abandoned.
// Rationale: 11 clean kernels with MLP 3-12, VGPR 36-116, waves 4-8/SIMD all
// land 33-40us; no pipe >55% utilized; combined traffic 3.7 TB/s vs 6.7
// proven by fillBuffer. Untested dimension: XCD data placement. Default
// round-robin puts y-adjacent tiles (6 shared halo rows) on different L2s
// and interleaves 8 images per XCD read stream. Swizzle: XCD k owns images
// 8k..8k+7; within an XCD, blocks walk one image's tiles y-adjacent-first.
#define HW 512
#define OW 506

typedef float vf4 __attribute__((ext_vector_type(4)));

// 3 x global_load_dwordx4; "=&v" early-clobber (v15 fault fix).
#define LOAD_ROW(d0, d1, d2, addr, O0, O1, O2)                        \
    asm volatile("global_load_dwordx4 %0, %3, off offset:" #O0 "\n\t" \
                 "global_load_dwordx4 %1, %3, off offset:" #O1 "\n\t" \
                 "global_load_dwordx4 %2, %3, off offset:" #O2        \
                 : "=&v"(d0), "=&v"(d1), "=&v"(d2)                    \
                 : "v"(addr) : "memory")

// Counted wait; tied "+v" operands pin consumer FMAs after the waitcnt.
#define WAIT_ROW(d0, d1, d2, N)                                       \
    asm volatile("s_waitcnt vmcnt(" #N ")"                            \
                 : "+v"(d0), "+v"(d1), "+v"(d2))

template<int SH>
__device__ __forceinline__ void row_fma(int ir, const vf4 (&b)[3],
                                        const float (&wv)[49],
                                        float (&acc)[32]) {
#pragma unroll
    for (int kr = 0; kr < 7; ++kr) {
        const int s = ir - kr;               // constant after caller unroll
        if (s >= 0 && s < 8) {
#pragma unroll
            for (int kc = 0; kc < 7; ++kc) {
                const float wk = wv[kr * 7 + kc];
#pragma unroll
                for (int j = 0; j < 4; ++j) {
                    const int e = SH + kc + j;          // 0..11, constant
                    acc[s * 4 + j] = fmaf(wk, b[e >> 2][e & 3], acc[s * 4 + j]);
                }
            }
        }
    }
}

template<int SH>
__device__ __forceinline__ void conv_pipe(const float* __restrict__ p0,
                                          const float (&wv)[49],
                                          float (&acc)[32]) {
    vf4 buf[4][3];                            // 4-row rotating buffer
    const float* a0 = p0;
    const float* a1 = p0 + 2 * HW;
    const float* a2 = p0 + 4 * HW;
    const float* a3 = p0 + 6 * HW;
    const float* a4 = p0 + 8 * HW;
    const float* a5 = p0 + 10 * HW;
    const float* a6 = p0 + 12 * HW;

    // prologue: rows 0..3 -> 12 loads in flight
    LOAD_ROW(buf[0][0], buf[0][1], buf[0][2], a0, 0, 16, 32);
    LOAD_ROW(buf[1][0], buf[1][1], buf[1][2], a0, 2048, 2064, 2080);
    LOAD_ROW(buf[2][0], buf[2][1], buf[2][2], a1, 0, 16, 32);
    LOAD_ROW(buf[3][0], buf[3][1], buf[3][2], a1, 2048, 2064, 2080);

    WAIT_ROW(buf[0][0], buf[0][1], buf[0][2], 9);
    row_fma<SH>(0, buf[0], wv, acc);
    LOAD_ROW(buf[0][0], buf[0][1], buf[0][2], a2, 0, 16, 32);        // row 4

    WAIT_ROW(buf[1][0], buf[1][1], buf[1][2], 9);
    row_fma<SH>(1, buf[1], wv, acc);
    LOAD_ROW(buf[1][0], buf[1][1], buf[1][2], a2, 2048, 2064, 2080); // row 5

    WAIT_ROW(buf[2][0], buf[2][1], buf[2][2], 9);
    row_fma<SH>(2, buf[2], wv, acc);
    LOAD_ROW(buf[2][0], buf[2][1], buf[2][2], a3, 0, 16, 32);        // row 6

    WAIT_ROW(buf[3][0], buf[3][1], buf[3][2], 9);
    row_fma<SH>(3, buf[3], wv, acc);
    LOAD_ROW(buf[3][0], buf[3][1], buf[3][2], a3, 2048, 2064, 2080); // row 7

    WAIT_ROW(buf[0][0], buf[0][1], buf[0][2], 9);
    row_fma<SH>(4, buf[0], wv, acc);
    LOAD_ROW(buf[0][0], buf[0][1], buf[0][2], a4, 0, 16, 32);        // row 8

    WAIT_ROW(buf[1][0], buf[1][1], buf[1][2], 9);
    row_fma<SH>(5, buf[1], wv, acc);
    LOAD_ROW(buf[1][0], buf[1][1], buf[1][2], a4, 2048, 2064, 2080); // row 9

    WAIT_ROW(buf[2][0], buf[2][1], buf[2][2], 9);
    row_fma<SH>(6, buf[2], wv, acc);
    LOAD_ROW(buf[2][0], buf[2][1], buf[2][2], a5, 0, 16, 32);        // row 10

    WAIT_ROW(buf[3][0], buf[3][1], buf[3][2], 9);
    row_fma<SH>(7, buf[3], wv, acc);
    LOAD_ROW(buf[3][0], buf[3][1], buf[3][2], a5, 2048, 2064, 2080); // row 11

    WAIT_ROW(buf[0][0], buf[0][1], buf[0][2], 9);
    row_fma<SH>(8, buf[0], wv, acc);
    LOAD_ROW(buf[0][0], buf[0][1], buf[0][2], a6, 0, 16, 32);        // row 12

    WAIT_ROW(buf[1][0], buf[1][1], buf[1][2], 9);
    row_fma<SH>(9, buf[1], wv, acc);
    LOAD_ROW(buf[1][0], buf[1][1], buf[1][2], a6, 2048, 2064, 2080); // row 13

    // epilogue: drain 9 -> 6 -> 3 -> 0
    WAIT_ROW(buf[2][0], buf[2][1], buf[2][2], 9);
    row_fma<SH>(10, buf[2], wv, acc);
    WAIT_ROW(buf[3][0], buf[3][1], buf[3][2], 6);
    row_fma<SH>(11, buf[3], wv, acc);
    WAIT_ROW(buf[0][0], buf[0][1], buf[0][2], 3);
    row_fma<SH>(12, buf[0], wv, acc);
    WAIT_ROW(buf[1][0], buf[1][1], buf[1][2], 0);
    row_fma<SH>(13, buf[1], wv, acc);
}

__global__ __launch_bounds__(256) void conv7x7_v21(
    const float* __restrict__ in,      // [64][512][512]
    const float* __restrict__ weight,  // [7][7]
    const float* __restrict__ bias,    // [1]
    float* __restrict__ out)           // [64][506][506]
{
    // ---- XCD-aware swizzle over a 1-D grid of 2048 blocks ----
    // dispatcher: consecutive bid -> round-robin XCD (bid & 7 = XCD).
    // XCD k owns images 8k..8k+7; within an XCD, slots walk one image's
    // 32 tiles (y-adjacent first), then the next image.
    const int bid  = blockIdx.x;
    const int xcd  = bid & 7;
    const int slot = bid >> 3;                  // 0..255 within XCD
    const int b    = xcd * 8 + (slot >> 5);     // image 0..63
    const int t    = slot & 31;                 // tile within image
    const int bx   = t & 1;                     // x-tile 0/1
    const int by   = t >> 1;                    // y-tile 0..15

    const int tid  = threadIdx.x;
    const int lane = tid & 63;
    const int w    = tid >> 6;
    const int x0   = bx ? 250 : 0;              // tiles cover 0..255, 250..505
    const int y0   = min(by * 32, OW - 32);     // shifted last tile
    const int yb   = y0 + w * 8;                // wave's first output row (<=498)

    // ---- weights + bias -> SGPRs (uniform, statically indexed) ----
    float wv[49];
#pragma unroll
    for (int i = 0; i < 49; ++i)
        wv[i] = __uint_as_float(__builtin_amdgcn_readfirstlane(__float_as_uint(weight[i])));
    const float bv = __uint_as_float(__builtin_amdgcn_readfirstlane(__float_as_uint(bias[0])));

    const float* __restrict__ ib = in + (size_t)b * (HW * HW);

    const int cb = x0 + 4 * lane;               // first output col (<=502)
    const float* p0 = ib + (size_t)yb * HW + (cb - (bx ? 2 : 0));

    float acc[32];
#pragma unroll
    for (int i = 0; i < 32; ++i) acc[i] = 0.f;

    if (bx == 0) conv_pipe<0>(p0, wv, acc);     // uniform SGPR branch
    else         conv_pipe<2>(p0, wv, acc);

    // ---- store: 8 rows x 4 cols, two float2 per row, unguarded ----
    float* __restrict__ outb = out + (size_t)b * (OW * OW);
#pragma unroll
    for (int s = 0; s < 8; ++s) {
        float* orow = outb + (size_t)(yb + s) * OW + cb;   // cb even -> 8B aligned
        *reinterpret_cast<float2*>(orow) =
            make_float2(acc[s * 4 + 0] + bv, acc[s * 4 + 1] + bv);
        *reinterpret_cast<float2*>(orow + 2) =
            make_float2(acc[s * 4 + 2] + bv, acc[s * 4 + 3] + bv);
    }
}

extern "C" void kernel_launch(void* const* d_in, const int* in_sizes, int n_in,
                              void* d_out, int out_size, void* d_ws, size_t ws_size,
                              hipStream_t stream) {
    const float* enc_x  = (const float*)d_in[0];
    const float* weight = (const float*)d_in[1];
    const float* bias   = (const float*)d_in[2];
    float* outp         = (float*)d_out;

    // 1-D grid: 2048 blocks = 64 images x 32 tiles, XCD-swizzled in-kernel.
    dim3 grid(2048);
    dim3 block(256);
    hipLaunchKernelGGL(conv7x7_v21, grid, block, 0, stream,
                       enc_x, weight, bias, outp);
}